// Round 1
// baseline (1137.677 us; speedup 1.0000x reference)
//
#include <hip/hip_runtime.h>
#include <math.h>

#define BB 32
#define NN 128
#define SEQL 336
#define PREDL 96
#define DINC 16
#define DEMBC 32
#define HIDC 64
#define GG 8
#define KWIN 25
#define ENDC 34
#define TT 432

// workspace offsets (floats)
#define OFF_SEAS   0
#define OFF_TREND  (OFF_SEAS + BB*NN*SEQL)
#define OFF_GIN    (OFF_TREND + BB*NN*SEQL)
#define OFF_GOUT   (OFF_GIN + GG*BB*SEQL)
#define OFF_SEASO  (OFF_GOUT + GG*BB*PREDL)
#define OFF_TRENDO (OFF_SEASO + BB*NN*PREDL)
#define OFF_HMEAN  (OFF_TRENDO + BB*NN*PREDL)
#define OFF_GX     (OFF_HMEAN + BB*TT*ENDC)

// output offsets (floats)
#define OUT_FORMER 0
#define OUT_ATTF   (BB*NN*SEQL)
#define OUT_AFTER  (OUT_ATTF + BB*SEQL)
#define OUT_ATTA   (OUT_AFTER + BB*NN*PREDL)

__device__ __forceinline__ float fsig(float x) { return 1.0f/(1.0f + __expf(-x)); }
__device__ __forceinline__ float ftanh(float x) { return 1.0f - 2.0f/(__expf(2.0f*x) + 1.0f); }

// K1: per-group mean over member nodes: g_in[g,b,s]
__global__ __launch_bounds__(384) void k_group_mean(const float* __restrict__ x,
                                                    const int* __restrict__ gi,
                                                    float* __restrict__ g_in) {
    int g = blockIdx.x, b = blockIdx.y;
    __shared__ int sgi[NN];
    __shared__ float scnt;
    int tid = threadIdx.x;
    if (tid < NN) sgi[tid] = gi[tid];
    __syncthreads();
    if (tid == 0) {
        int c = 0;
        for (int n = 0; n < NN; n++) if (sgi[n] == g) c++;
        scnt = (float)c;
    }
    __syncthreads();
    float inv = 1.0f / scnt;
    for (int s = tid; s < SEQL; s += 384) {
        float sum = 0.0f;
        for (int n = 0; n < NN; n++)
            if (sgi[n] == g) sum += x[(b*NN + n)*SEQL + s];
        g_in[(g*BB + b)*SEQL + s] = sum * inv;
    }
}

// K2: g_out[g,b,p] = w_res[g,p,:] . g_in[g,b,:] + b_res[g,p]
__global__ void k_gout(const float* __restrict__ g_in, const float* __restrict__ w_res,
                       const float* __restrict__ b_res, float* __restrict__ g_out) {
    int idx = blockIdx.x*blockDim.x + threadIdx.x;
    if (idx >= GG*BB*PREDL) return;
    int p = idx % PREDL;
    int b = (idx / PREDL) % BB;
    int g = idx / (PREDL*BB);
    const float* gr = g_in + (g*BB + b)*SEQL;
    const float* wr = w_res + (g*PREDL + p)*SEQL;
    float acc = b_res[g*PREDL + p];
    for (int s = 0; s < SEQL; s++) acc += gr[s]*wr[s];
    g_out[idx] = acc;
}

// K3: series decomposition: edge-padded moving average window 25
__global__ void k_decomp(const float* __restrict__ x, float* __restrict__ seasonal,
                         float* __restrict__ trend) {
    int idx = blockIdx.x*blockDim.x + threadIdx.x;
    if (idx >= BB*NN*SEQL) return;
    int t = idx % SEQL;
    int bn = idx / SEQL;
    const float* xr = x + bn*SEQL;
    float s = 0.0f;
    #pragma unroll
    for (int d = -12; d <= 12; d++) {
        int j = t + d;
        j = j < 0 ? 0 : (j >= SEQL ? SEQL-1 : j);
        s += xr[j];
    }
    float tr = s * (1.0f/KWIN);
    trend[idx] = tr;
    seasonal[idx] = xr[t] - tr;
}

// K4: per-node grouped seasonal/trend heads (SEQ->PRED)
__global__ __launch_bounds__(128) void k_heads(const float* __restrict__ seasonal,
                                               const float* __restrict__ trend,
                                               const int* __restrict__ gi,
                                               const float* __restrict__ w_seas,
                                               const float* __restrict__ b_seas,
                                               const float* __restrict__ w_trend,
                                               const float* __restrict__ b_trend,
                                               float* __restrict__ seas_out,
                                               float* __restrict__ trend_out) {
    int bn = blockIdx.x;
    int n = bn % NN;
    int g = gi[n];
    __shared__ float ss[SEQL];
    __shared__ float st[SEQL];
    for (int s = threadIdx.x; s < SEQL; s += 128) {
        ss[s] = seasonal[bn*SEQL + s];
        st[s] = trend[bn*SEQL + s];
    }
    __syncthreads();
    int p = threadIdx.x;
    if (p < PREDL) {
        const float* wsr = w_seas + (g*PREDL + p)*SEQL;
        const float* wtr = w_trend + (g*PREDL + p)*SEQL;
        float a = b_seas[g*PREDL + p];
        float c = b_trend[g*PREDL + p];
        for (int s = 0; s < SEQL; s++) { a += ss[s]*wsr[s]; c += st[s]*wtr[s]; }
        seas_out[bn*PREDL + p] = a;
        trend_out[bn*PREDL + p] = c;
    }
}

// K5: fused dy-embedding + end-MLP (former & after) + residual add
__global__ __launch_bounds__(512) void k_mlp(
    const float* __restrict__ seasonal, const float* __restrict__ trend,
    const float* __restrict__ seas_out, const float* __restrict__ trend_out,
    const float* __restrict__ g_in, const float* __restrict__ g_out,
    const int* __restrict__ gi, const float* __restrict__ dy,
    const float* __restrict__ dy_w, const float* __restrict__ dy_b,
    const float* __restrict__ w1_end, const float* __restrict__ b1_end,
    const float* __restrict__ w2_end, const float* __restrict__ b2_end,
    float* __restrict__ out)
{
    int bn = blockIdx.x;
    int b = bn / NN, n = bn % NN;
    int g = gi[n];
    __shared__ float sw1[HIDC][36];
    __shared__ float sb1[HIDC];
    __shared__ float sw2[HIDC];
    __shared__ float sdyw[DEMBC][DINC];
    __shared__ float sdyb[DEMBC];
    __shared__ float sb2[1];
    int tid = threadIdx.x;
    for (int i = tid; i < HIDC*36; i += 512) {
        int h = i / 36, e = i % 36;
        sw1[h][e] = (e < ENDC) ? w1_end[(g*HIDC + h)*ENDC + e] : 0.0f;
    }
    if (tid < HIDC) { sb1[tid] = b1_end[g*HIDC + tid]; sw2[tid] = w2_end[g*HIDC + tid]; }
    if (tid < DEMBC) sdyb[tid] = dy_b[tid];
    for (int i = tid; i < DEMBC*DINC; i += 512) sdyw[i/DINC][i%DINC] = dy_w[i];
    if (tid == 0) sb2[0] = b2_end[g];
    __syncthreads();
    int t = tid;
    if (t >= TT) return;
    float hv[36];
    const float* dyr = dy + ((size_t)bn*TT + t)*DINC;
    float dv[DINC];
    #pragma unroll
    for (int i = 0; i < DINC; i++) dv[i] = dyr[i];
    #pragma unroll 4
    for (int e = 0; e < DEMBC; e++) {
        float a = sdyb[e];
        #pragma unroll
        for (int i = 0; i < DINC; i++) a += dv[i]*sdyw[e][i];
        hv[2+e] = fmaxf(a, 0.0f);
    }
    float addv;
    if (t < SEQL) {
        hv[0] = seasonal[bn*SEQL + t];
        hv[1] = trend[bn*SEQL + t];
        addv = g_in[(g*BB + b)*SEQL + t];
    } else {
        int p = t - SEQL;
        hv[0] = seas_out[bn*PREDL + p];
        hv[1] = trend_out[bn*PREDL + p];
        addv = g_out[(g*BB + b)*PREDL + p];
    }
    hv[34] = 0.0f; hv[35] = 0.0f;
    float acc = sb2[0];
    #pragma unroll 4
    for (int h = 0; h < HIDC; h++) {
        float a = sb1[h];
        #pragma unroll
        for (int e4 = 0; e4 < 36; e4 += 4) {
            float4 w = *(const float4*)&sw1[h][e4];
            a += w.x*hv[e4] + w.y*hv[e4+1] + w.z*hv[e4+2] + w.w*hv[e4+3];
        }
        acc += fmaxf(a, 0.0f) * sw2[h];
    }
    acc += addv;
    if (t < SEQL) out[OUT_FORMER + bn*SEQL + t] = acc;
    else          out[OUT_AFTER + bn*PREDL + (t - SEQL)] = acc;
}

// K6: node-mean of the hidden vector (34 channels) per (b,t)
__global__ __launch_bounds__(64) void k_hmean(
    const float* __restrict__ seasonal, const float* __restrict__ trend,
    const float* __restrict__ seas_out, const float* __restrict__ trend_out,
    const float* __restrict__ dy, const float* __restrict__ dy_w,
    const float* __restrict__ dy_b, float* __restrict__ hmean)
{
    int bt = blockIdx.x;
    int b = bt / TT, t = bt % TT;
    int lane = threadIdx.x;
    __shared__ float sdyw[DEMBC][DINC];
    __shared__ float sdyb[DEMBC];
    for (int i = lane; i < DEMBC*DINC; i += 64) sdyw[i/DINC][i%DINC] = dy_w[i];
    if (lane < DEMBC) sdyb[lane] = dy_b[lane];
    __syncthreads();
    float v[ENDC];
    #pragma unroll
    for (int e = 0; e < ENDC; e++) v[e] = 0.0f;
    #pragma unroll
    for (int q = 0; q < 2; q++) {
        int n = lane + q*64;
        int bn = b*NN + n;
        if (t < SEQL) {
            v[0] += seasonal[bn*SEQL + t];
            v[1] += trend[bn*SEQL + t];
        } else {
            int p = t - SEQL;
            v[0] += seas_out[bn*PREDL + p];
            v[1] += trend_out[bn*PREDL + p];
        }
        const float* dyr = dy + ((size_t)bn*TT + t)*DINC;
        float dv[DINC];
        #pragma unroll
        for (int i = 0; i < DINC; i++) dv[i] = dyr[i];
        #pragma unroll 4
        for (int e = 0; e < DEMBC; e++) {
            float a = sdyb[e];
            #pragma unroll
            for (int i = 0; i < DINC; i++) a += dv[i]*sdyw[e][i];
            v[2+e] += fmaxf(a, 0.0f);
        }
    }
    #pragma unroll
    for (int e = 0; e < ENDC; e++) {
        float s = v[e];
        s += __shfl_xor(s, 32, 64);
        s += __shfl_xor(s, 16, 64);
        s += __shfl_xor(s, 8, 64);
        s += __shfl_xor(s, 4, 64);
        s += __shfl_xor(s, 2, 64);
        s += __shfl_xor(s, 1, 64);
        v[e] = s;
    }
    if (lane == 0) {
        #pragma unroll
        for (int e = 0; e < ENDC; e++) hmean[(size_t)bt*ENDC + e] = v[e] * (1.0f/NN);
    }
}

// K7: input-side GRU gates gx[b,t,j] = hmean[b,t,:] . w_ih[j,:] + b_ih[j]
__global__ void k_gx(const float* __restrict__ hmean, const float* __restrict__ w_ih,
                     const float* __restrict__ b_ih, float* __restrict__ gx) {
    int idx = blockIdx.x*blockDim.x + threadIdx.x;
    if (idx >= BB*TT*3*HIDC) return;
    int j = idx % 192;
    int bt = idx / 192;
    const float* hm = hmean + (size_t)bt*ENDC;
    const float* w = w_ih + j*ENDC;
    float a = b_ih[j];
    #pragma unroll
    for (int e = 0; e < ENDC; e++) a += hm[e]*w[e];
    gx[idx] = a;
}

// K8: dual GRU (blocks 0..31 former over SEQ, 32..63 after over PRED) + attention proj
__global__ __launch_bounds__(64) void k_gru(
    const float* __restrict__ gx, const float* __restrict__ w_hh,
    const float* __restrict__ b_hh, const float* __restrict__ w_ap,
    const float* __restrict__ b_ap, float* __restrict__ out)
{
    int blk = blockIdx.x;
    int b = blk & 31;
    int former = (blk < 32) ? 1 : 0;
    int steps = former ? SEQL : PREDL;
    int t0 = former ? 0 : SEQL;
    float* attn = out + (former ? (OUT_ATTF + b*SEQL) : (OUT_ATTA + b*PREDL));
    int lane = threadIdx.x;
    float wr[HIDC], wz[HIDC], wn[HIDC];
    #pragma unroll
    for (int k = 0; k < HIDC; k++) {
        wr[k] = w_hh[lane*HIDC + k];
        wz[k] = w_hh[(lane+64)*HIDC + k];
        wn[k] = w_hh[(lane+128)*HIDC + k];
    }
    float bhr = b_hh[lane], bhz = b_hh[lane+64], bhn = b_hh[lane+128];
    float wap = w_ap[lane], bap = b_ap[0];
    __shared__ __align__(16) float hs[HIDC];
    hs[lane] = 0.0f;
    float h = 0.0f;
    __syncthreads();
    const float* gxb = gx + (size_t)(b*TT + t0)*192;
    float gr = gxb[lane], gz = gxb[64+lane], gn = gxb[128+lane];
    for (int s = 0; s < steps; s++) {
        float nr = 0.0f, nz = 0.0f, nn2 = 0.0f;
        if (s+1 < steps) {
            const float* gp = gxb + (size_t)(s+1)*192;
            nr = gp[lane]; nz = gp[64+lane]; nn2 = gp[128+lane];
        }
        float ar = 0.0f, az = 0.0f, an = 0.0f;
        #pragma unroll
        for (int k = 0; k < HIDC; k += 4) {
            float4 hh = *(const float4*)&hs[k];
            ar += hh.x*wr[k] + hh.y*wr[k+1] + hh.z*wr[k+2] + hh.w*wr[k+3];
            az += hh.x*wz[k] + hh.y*wz[k+1] + hh.z*wz[k+2] + hh.w*wz[k+3];
            an += hh.x*wn[k] + hh.y*wn[k+1] + hh.z*wn[k+2] + hh.w*wn[k+3];
        }
        float r = fsig(gr + bhr + ar);
        float z = fsig(gz + bhz + az);
        float tg = ftanh(gn + r*(bhn + an));
        h = (1.0f - z)*tg + z*h;
        float satt = wap * h;
        satt += __shfl_xor(satt, 32, 64);
        satt += __shfl_xor(satt, 16, 64);
        satt += __shfl_xor(satt, 8, 64);
        satt += __shfl_xor(satt, 4, 64);
        satt += __shfl_xor(satt, 2, 64);
        satt += __shfl_xor(satt, 1, 64);
        if (lane == 0) attn[s] = fsig(satt + bap);
        __syncthreads();
        hs[lane] = h;
        __syncthreads();
        gr = nr; gz = nz; gn = nn2;
    }
}

extern "C" void kernel_launch(void* const* d_in, const int* in_sizes, int n_in,
                              void* d_out, int out_size, void* d_ws, size_t ws_size,
                              hipStream_t stream) {
    (void)in_sizes; (void)n_in; (void)out_size; (void)ws_size;
    const float* x       = (const float*)d_in[0];
    const float* dy      = (const float*)d_in[1];
    const int*   gi      = (const int*)  d_in[2];
    const float* dy_w    = (const float*)d_in[3];
    const float* dy_b    = (const float*)d_in[4];
    const float* w_seas  = (const float*)d_in[5];
    const float* b_seas  = (const float*)d_in[6];
    const float* w_trend = (const float*)d_in[7];
    const float* b_trend = (const float*)d_in[8];
    const float* w_res   = (const float*)d_in[9];
    const float* b_res   = (const float*)d_in[10];
    const float* w1_end  = (const float*)d_in[11];
    const float* b1_end  = (const float*)d_in[12];
    const float* w2_end  = (const float*)d_in[13];
    const float* b2_end  = (const float*)d_in[14];
    const float* w_ih    = (const float*)d_in[15];
    const float* w_hh    = (const float*)d_in[16];
    const float* b_ih    = (const float*)d_in[17];
    const float* b_hh    = (const float*)d_in[18];
    const float* w_ap    = (const float*)d_in[19];
    const float* b_ap    = (const float*)d_in[20];
    float* ws  = (float*)d_ws;
    float* out = (float*)d_out;

    hipLaunchKernelGGL(k_group_mean, dim3(GG, BB), dim3(384), 0, stream, x, gi, ws + OFF_GIN);
    hipLaunchKernelGGL(k_decomp, dim3((BB*NN*SEQL + 255)/256), dim3(256), 0, stream,
                       x, ws + OFF_SEAS, ws + OFF_TREND);
    hipLaunchKernelGGL(k_gout, dim3((GG*BB*PREDL + 255)/256), dim3(256), 0, stream,
                       ws + OFF_GIN, w_res, b_res, ws + OFF_GOUT);
    hipLaunchKernelGGL(k_heads, dim3(BB*NN), dim3(128), 0, stream,
                       ws + OFF_SEAS, ws + OFF_TREND, gi, w_seas, b_seas, w_trend, b_trend,
                       ws + OFF_SEASO, ws + OFF_TRENDO);
    hipLaunchKernelGGL(k_mlp, dim3(BB*NN), dim3(512), 0, stream,
                       ws + OFF_SEAS, ws + OFF_TREND, ws + OFF_SEASO, ws + OFF_TRENDO,
                       ws + OFF_GIN, ws + OFF_GOUT, gi, dy, dy_w, dy_b,
                       w1_end, b1_end, w2_end, b2_end, out);
    hipLaunchKernelGGL(k_hmean, dim3(BB*TT), dim3(64), 0, stream,
                       ws + OFF_SEAS, ws + OFF_TREND, ws + OFF_SEASO, ws + OFF_TRENDO,
                       dy, dy_w, dy_b, ws + OFF_HMEAN);
    hipLaunchKernelGGL(k_gx, dim3((BB*TT*192 + 255)/256), dim3(256), 0, stream,
                       ws + OFF_HMEAN, w_ih, b_ih, ws + OFF_GX);
    hipLaunchKernelGGL(k_gru, dim3(64), dim3(64), 0, stream,
                       ws + OFF_GX, w_hh, b_hh, w_ap, b_ap, out);
}

// Round 2
// 1060.349 us; speedup vs baseline: 1.0729x; 1.0729x over previous
//
#include <hip/hip_runtime.h>
#include <math.h>

#define BB 32
#define NN 128
#define SEQL 336
#define PREDL 96
#define DINC 16
#define DEMBC 32
#define HIDC 64
#define GG 8
#define KWIN 25
#define ENDC 34
#define TT 432

// workspace offsets (floats)
#define OFF_SEAS   0
#define OFF_TREND  (OFF_SEAS + BB*NN*SEQL)
#define OFF_GIN    (OFF_TREND + BB*NN*SEQL)
#define OFF_GOUT   (OFF_GIN + GG*BB*SEQL)
#define OFF_SEASO  (OFF_GOUT + GG*BB*PREDL)
#define OFF_TRENDO (OFF_SEASO + BB*NN*PREDL)
#define OFF_GX     (OFF_TRENDO + BB*NN*PREDL)
#define OFF_HIST   (OFF_GX + BB*TT*192)
// hist: former [32][336][64] then after [32][96][64]

// output offsets (floats)
#define OUT_FORMER 0
#define OUT_ATTF   (BB*NN*SEQL)
#define OUT_AFTER  (OUT_ATTF + BB*SEQL)
#define OUT_ATTA   (OUT_AFTER + BB*NN*PREDL)

__device__ __forceinline__ float fsig(float x) { return 1.0f/(1.0f + __expf(-x)); }
__device__ __forceinline__ float ftanh(float x) { return 1.0f - 2.0f/(__expf(2.0f*x) + 1.0f); }

// K1: per-group mean over member nodes: g_in[g,b,s]
__global__ __launch_bounds__(384) void k_group_mean(const float* __restrict__ x,
                                                    const int* __restrict__ gi,
                                                    float* __restrict__ g_in) {
    int g = blockIdx.x, b = blockIdx.y;
    __shared__ int sgi[NN];
    __shared__ float scnt;
    int tid = threadIdx.x;
    if (tid < NN) sgi[tid] = gi[tid];
    __syncthreads();
    if (tid == 0) {
        int c = 0;
        for (int n = 0; n < NN; n++) if (sgi[n] == g) c++;
        scnt = (float)c;
    }
    __syncthreads();
    float inv = 1.0f / scnt;
    for (int s = tid; s < SEQL; s += 384) {
        float sum = 0.0f;
        for (int n = 0; n < NN; n++)
            if (sgi[n] == g) sum += x[(b*NN + n)*SEQL + s];
        g_in[(g*BB + b)*SEQL + s] = sum * inv;
    }
}

// K2: g_out[g,b,p] = w_res[g,p,:] . g_in[g,b,:] + b_res[g,p]
__global__ void k_gout(const float* __restrict__ g_in, const float* __restrict__ w_res,
                       const float* __restrict__ b_res, float* __restrict__ g_out) {
    int idx = blockIdx.x*blockDim.x + threadIdx.x;
    if (idx >= GG*BB*PREDL) return;
    int p = idx % PREDL;
    int b = (idx / PREDL) % BB;
    int g = idx / (PREDL*BB);
    const float* gr = g_in + (g*BB + b)*SEQL;
    const float* wr = w_res + (g*PREDL + p)*SEQL;
    float acc = b_res[g*PREDL + p];
    for (int s = 0; s < SEQL; s++) acc += gr[s]*wr[s];
    g_out[idx] = acc;
}

// K3: series decomposition: edge-padded moving average window 25
__global__ void k_decomp(const float* __restrict__ x, float* __restrict__ seasonal,
                         float* __restrict__ trend) {
    int idx = blockIdx.x*blockDim.x + threadIdx.x;
    if (idx >= BB*NN*SEQL) return;
    int t = idx % SEQL;
    int bn = idx / SEQL;
    const float* xr = x + bn*SEQL;
    float s = 0.0f;
    #pragma unroll
    for (int d = -12; d <= 12; d++) {
        int j = t + d;
        j = j < 0 ? 0 : (j >= SEQL ? SEQL-1 : j);
        s += xr[j];
    }
    float tr = s * (1.0f/KWIN);
    trend[idx] = tr;
    seasonal[idx] = xr[t] - tr;
}

// K4: per-node grouped seasonal/trend heads (SEQ->PRED)
__global__ __launch_bounds__(128) void k_heads(const float* __restrict__ seasonal,
                                               const float* __restrict__ trend,
                                               const int* __restrict__ gi,
                                               const float* __restrict__ w_seas,
                                               const float* __restrict__ b_seas,
                                               const float* __restrict__ w_trend,
                                               const float* __restrict__ b_trend,
                                               float* __restrict__ seas_out,
                                               float* __restrict__ trend_out) {
    int bn = blockIdx.x;
    int n = bn % NN;
    int g = gi[n];
    __shared__ float ss[SEQL];
    __shared__ float st[SEQL];
    for (int s = threadIdx.x; s < SEQL; s += 128) {
        ss[s] = seasonal[bn*SEQL + s];
        st[s] = trend[bn*SEQL + s];
    }
    __syncthreads();
    int p = threadIdx.x;
    if (p < PREDL) {
        const float* wsr = w_seas + (g*PREDL + p)*SEQL;
        const float* wtr = w_trend + (g*PREDL + p)*SEQL;
        float a = b_seas[g*PREDL + p];
        float c = b_trend[g*PREDL + p];
        for (int s = 0; s < SEQL; s++) { a += ss[s]*wsr[s]; c += st[s]*wtr[s]; }
        seas_out[bn*PREDL + p] = a;
        trend_out[bn*PREDL + p] = c;
    }
}

// K5: node-mean of hidden (34 ch) per (b,t), fused with input-gate GEMM gx
__global__ __launch_bounds__(64) void k_hmean_gx(
    const float* __restrict__ seasonal, const float* __restrict__ trend,
    const float* __restrict__ seas_out, const float* __restrict__ trend_out,
    const float* __restrict__ dy, const float* __restrict__ dy_w,
    const float* __restrict__ dy_b, const float* __restrict__ w_ih,
    const float* __restrict__ b_ih, const float* __restrict__ b_hh,
    float* __restrict__ gx)
{
    int bt = blockIdx.x;
    int b = bt / TT, t = bt % TT;
    int lane = threadIdx.x;
    __shared__ float sdyw[DEMBC][DINC];
    __shared__ float sdyb[DEMBC];
    for (int i = lane; i < DEMBC*DINC; i += 64) sdyw[i/DINC][i%DINC] = dy_w[i];
    if (lane < DEMBC) sdyb[lane] = dy_b[lane];
    __syncthreads();
    float v[ENDC];
    #pragma unroll
    for (int e = 0; e < ENDC; e++) v[e] = 0.0f;
    #pragma unroll
    for (int q = 0; q < 2; q++) {
        int n = lane + q*64;
        int bn = b*NN + n;
        if (t < SEQL) {
            v[0] += seasonal[bn*SEQL + t];
            v[1] += trend[bn*SEQL + t];
        } else {
            int p = t - SEQL;
            v[0] += seas_out[bn*PREDL + p];
            v[1] += trend_out[bn*PREDL + p];
        }
        const float* dyr = dy + ((size_t)bn*TT + t)*DINC;
        float dv[DINC];
        #pragma unroll
        for (int i = 0; i < DINC; i++) dv[i] = dyr[i];
        #pragma unroll 4
        for (int e = 0; e < DEMBC; e++) {
            float a = sdyb[e];
            #pragma unroll
            for (int i = 0; i < DINC; i++) a += dv[i]*sdyw[e][i];
            v[2+e] += fmaxf(a, 0.0f);
        }
    }
    // butterfly all-reduce: every lane ends with the full sum
    #pragma unroll
    for (int e = 0; e < ENDC; e++) {
        float s = v[e];
        s += __shfl_xor(s, 32, 64);
        s += __shfl_xor(s, 16, 64);
        s += __shfl_xor(s, 8, 64);
        s += __shfl_xor(s, 4, 64);
        s += __shfl_xor(s, 2, 64);
        s += __shfl_xor(s, 1, 64);
        v[e] = s * (1.0f/NN);
    }
    // input-side gates: lane j emits gx[bt][j], [bt][64+j], [bt][128+j]
    // fold b_hh into r,z gates (their hidden-side bias is additive pre-sigmoid)
    #pragma unroll
    for (int gate = 0; gate < 3; gate++) {
        int j = gate*64 + lane;
        const float* w = w_ih + j*ENDC;
        float a = b_ih[j] + (gate < 2 ? b_hh[j] : 0.0f);
        #pragma unroll
        for (int e = 0; e < ENDC; e++) a = fmaf(v[e], w[e], a);
        gx[(size_t)bt*192 + j] = a;
    }
}

// K6: fused MLP (blocks 64..4159) + dual GRU (blocks 0..63, dispatched first
// so the 64 latency-bound GRU waves overlap with the MLP bulk).
__global__ __launch_bounds__(512) void k_mlp_gru(
    const float* __restrict__ seasonal, const float* __restrict__ trend,
    const float* __restrict__ seas_out, const float* __restrict__ trend_out,
    const float* __restrict__ g_in, const float* __restrict__ g_out,
    const int* __restrict__ gi, const float* __restrict__ dy,
    const float* __restrict__ dy_w, const float* __restrict__ dy_b,
    const float* __restrict__ w1_end, const float* __restrict__ b1_end,
    const float* __restrict__ w2_end, const float* __restrict__ b2_end,
    const float* __restrict__ gx, const float* __restrict__ w_hh,
    const float* __restrict__ b_hh, const float* __restrict__ w_ap,
    const float* __restrict__ b_ap, float* __restrict__ hist,
    float* __restrict__ out)
{
    __shared__ union {
        struct {
            float w1[HIDC][36];
            float b1[HIDC];
            float w2[HIDC];
            float dyw[DEMBC][DINC];
            float dyb[DEMBC];
            float b2;
        } mlp;
        struct { float hs[2*HIDC]; } gru;
    } sm;

    int tid = threadIdx.x;

    if (blockIdx.x < 64) {
        // ---------------- GRU path: single wave, weights in registers ----------------
        if (tid >= 64) return;
        int lane = tid;
        int blk = blockIdx.x;
        int b = blk & 31;
        bool former = (blk < 32);
        int steps = former ? SEQL : PREDL;
        int t0 = former ? 0 : SEQL;
        float* hb = hist + (former ? (size_t)b*SEQL*HIDC
                                   : (size_t)BB*SEQL*HIDC + (size_t)b*PREDL*HIDC);
        // fully unrolled preload -> static indices -> stays in VGPRs (rule #20)
        float wr_[HIDC], wz_[HIDC], wn_[HIDC];
        #pragma unroll
        for (int k = 0; k < HIDC; k++) wr_[k] = w_hh[lane*HIDC + k];
        #pragma unroll
        for (int k = 0; k < HIDC; k++) wz_[k] = w_hh[(lane+64)*HIDC + k];
        #pragma unroll
        for (int k = 0; k < HIDC; k++) wn_[k] = w_hh[(lane+128)*HIDC + k];
        float bhn = b_hh[lane + 128];
        sm.gru.hs[lane] = 0.0f;   // row 0 = h_{-1} = 0 (single wave: lgkmcnt orders)
        float h = 0.0f;
        const float* gxb = gx + (size_t)(b*TT + t0)*192;
        // depth-2 gx prefetch
        float c_r = gxb[lane], c_z = gxb[64+lane], c_n = gxb[128+lane];
        float n_r = 0.f, n_z = 0.f, n_n = 0.f;
        if (steps > 1) { n_r = gxb[192+lane]; n_z = gxb[256+lane]; n_n = gxb[320+lane]; }
        for (int s = 0; s < steps; s++) {
            float p_r = 0.f, p_z = 0.f, p_n = 0.f;
            if (s + 2 < steps) {
                const float* gp = gxb + (size_t)(s+2)*192;
                p_r = gp[lane]; p_z = gp[64+lane]; p_n = gp[128+lane];
            }
            const float* hh = sm.gru.hs + (s & 1)*HIDC;
            float ar = 0.f, az = 0.f, an = 0.f;
            #pragma unroll
            for (int k = 0; k < HIDC; k += 4) {
                float4 h4 = *(const float4*)&hh[k];
                ar = fmaf(h4.x, wr_[k],   ar); az = fmaf(h4.x, wz_[k],   az); an = fmaf(h4.x, wn_[k],   an);
                ar = fmaf(h4.y, wr_[k+1], ar); az = fmaf(h4.y, wz_[k+1], az); an = fmaf(h4.y, wn_[k+1], an);
                ar = fmaf(h4.z, wr_[k+2], ar); az = fmaf(h4.z, wz_[k+2], az); an = fmaf(h4.z, wn_[k+2], an);
                ar = fmaf(h4.w, wr_[k+3], ar); az = fmaf(h4.w, wz_[k+3], az); an = fmaf(h4.w, wn_[k+3], an);
            }
            float r = fsig(c_r + ar);          // b_ih + b_hh folded into gx
            float z = fsig(c_z + az);
            float tg = ftanh(c_n + r*(bhn + an));
            h = (1.0f - z)*tg + z*h;
            sm.gru.hs[((s+1) & 1)*HIDC + lane] = h;
            hb[(size_t)s*HIDC + lane] = h;     // fire-and-forget history store
            c_r = n_r; c_z = n_z; c_n = n_n;
            n_r = p_r; n_z = p_z; n_n = p_n;
        }
        // attention epilogue from history (own writes; same-address ordering via vmcnt)
        float bap = b_ap[0];
        float* attn = out + (former ? (OUT_ATTF + b*SEQL) : (OUT_ATTA + b*PREDL));
        for (int t = lane; t < steps; t += 64) {
            const float* hr = hb + (size_t)t*HIDC;
            float a = 0.f;
            #pragma unroll 16
            for (int k = 0; k < HIDC; k++) a = fmaf(hr[k], w_ap[k], a);
            attn[t] = fsig(a + bap);
        }
        return;
    }

    // ---------------- MLP path ----------------
    int bn = blockIdx.x - 64;
    int b = bn / NN, n = bn % NN;
    int g = gi[n];
    for (int i = tid; i < HIDC*36; i += 512) {
        int hh = i / 36, e = i % 36;
        sm.mlp.w1[hh][e] = (e < ENDC) ? w1_end[(g*HIDC + hh)*ENDC + e] : 0.0f;
    }
    if (tid < HIDC) { sm.mlp.b1[tid] = b1_end[g*HIDC + tid]; sm.mlp.w2[tid] = w2_end[g*HIDC + tid]; }
    if (tid < DEMBC) sm.mlp.dyb[tid] = dy_b[tid];
    for (int i = tid; i < DEMBC*DINC; i += 512) sm.mlp.dyw[i/DINC][i%DINC] = dy_w[i];
    if (tid == 0) sm.mlp.b2 = b2_end[g];
    __syncthreads();
    int t = tid;
    if (t >= TT) return;
    float hv[36];
    const float* dyr = dy + ((size_t)bn*TT + t)*DINC;
    float dv[DINC];
    #pragma unroll
    for (int i = 0; i < DINC; i++) dv[i] = dyr[i];
    #pragma unroll 4
    for (int e = 0; e < DEMBC; e++) {
        float a = sm.mlp.dyb[e];
        #pragma unroll
        for (int i = 0; i < DINC; i++) a += dv[i]*sm.mlp.dyw[e][i];
        hv[2+e] = fmaxf(a, 0.0f);
    }
    float addv;
    if (t < SEQL) {
        hv[0] = seasonal[bn*SEQL + t];
        hv[1] = trend[bn*SEQL + t];
        addv = g_in[(g*BB + b)*SEQL + t];
    } else {
        int p = t - SEQL;
        hv[0] = seas_out[bn*PREDL + p];
        hv[1] = trend_out[bn*PREDL + p];
        addv = g_out[(g*BB + b)*PREDL + p];
    }
    hv[34] = 0.0f; hv[35] = 0.0f;
    float acc = sm.mlp.b2;
    #pragma unroll 4
    for (int hq = 0; hq < HIDC; hq++) {
        float a = sm.mlp.b1[hq];
        #pragma unroll
        for (int e4 = 0; e4 < 36; e4 += 4) {
            float4 w = *(const float4*)&sm.mlp.w1[hq][e4];
            a += w.x*hv[e4] + w.y*hv[e4+1] + w.z*hv[e4+2] + w.w*hv[e4+3];
        }
        acc += fmaxf(a, 0.0f) * sm.mlp.w2[hq];
    }
    acc += addv;
    if (t < SEQL) out[OUT_FORMER + bn*SEQL + t] = acc;
    else          out[OUT_AFTER + bn*PREDL + (t - SEQL)] = acc;
}

extern "C" void kernel_launch(void* const* d_in, const int* in_sizes, int n_in,
                              void* d_out, int out_size, void* d_ws, size_t ws_size,
                              hipStream_t stream) {
    (void)in_sizes; (void)n_in; (void)out_size; (void)ws_size;
    const float* x       = (const float*)d_in[0];
    const float* dy      = (const float*)d_in[1];
    const int*   gi      = (const int*)  d_in[2];
    const float* dy_w    = (const float*)d_in[3];
    const float* dy_b    = (const float*)d_in[4];
    const float* w_seas  = (const float*)d_in[5];
    const float* b_seas  = (const float*)d_in[6];
    const float* w_trend = (const float*)d_in[7];
    const float* b_trend = (const float*)d_in[8];
    const float* w_res   = (const float*)d_in[9];
    const float* b_res   = (const float*)d_in[10];
    const float* w1_end  = (const float*)d_in[11];
    const float* b1_end  = (const float*)d_in[12];
    const float* w2_end  = (const float*)d_in[13];
    const float* b2_end  = (const float*)d_in[14];
    const float* w_ih    = (const float*)d_in[15];
    const float* w_hh    = (const float*)d_in[16];
    const float* b_ih    = (const float*)d_in[17];
    const float* b_hh    = (const float*)d_in[18];
    const float* w_ap    = (const float*)d_in[19];
    const float* b_ap    = (const float*)d_in[20];
    float* ws  = (float*)d_ws;
    float* out = (float*)d_out;

    hipLaunchKernelGGL(k_group_mean, dim3(GG, BB), dim3(384), 0, stream, x, gi, ws + OFF_GIN);
    hipLaunchKernelGGL(k_decomp, dim3((BB*NN*SEQL + 255)/256), dim3(256), 0, stream,
                       x, ws + OFF_SEAS, ws + OFF_TREND);
    hipLaunchKernelGGL(k_gout, dim3((GG*BB*PREDL + 255)/256), dim3(256), 0, stream,
                       ws + OFF_GIN, w_res, b_res, ws + OFF_GOUT);
    hipLaunchKernelGGL(k_heads, dim3(BB*NN), dim3(128), 0, stream,
                       ws + OFF_SEAS, ws + OFF_TREND, gi, w_seas, b_seas, w_trend, b_trend,
                       ws + OFF_SEASO, ws + OFF_TRENDO);
    hipLaunchKernelGGL(k_hmean_gx, dim3(BB*TT), dim3(64), 0, stream,
                       ws + OFF_SEAS, ws + OFF_TREND, ws + OFF_SEASO, ws + OFF_TRENDO,
                       dy, dy_w, dy_b, w_ih, b_ih, b_hh, ws + OFF_GX);
    hipLaunchKernelGGL(k_mlp_gru, dim3(64 + BB*NN), dim3(512), 0, stream,
                       ws + OFF_SEAS, ws + OFF_TREND, ws + OFF_SEASO, ws + OFF_TRENDO,
                       ws + OFF_GIN, ws + OFF_GOUT, gi, dy, dy_w, dy_b,
                       w1_end, b1_end, w2_end, b2_end,
                       ws + OFF_GX, w_hh, b_hh, w_ap, b_ap, ws + OFF_HIST, out);
}

// Round 3
// 848.789 us; speedup vs baseline: 1.3404x; 1.2492x over previous
//
#include <hip/hip_runtime.h>
#include <math.h>

#define BB 32
#define NN 128
#define SEQL 336
#define PREDL 96
#define DINC 16
#define DEMBC 32
#define HIDC 64
#define GG 8
#define KWIN 25
#define ENDC 34
#define TT 432

// workspace offsets (floats)
#define OFF_SEAS   0
#define OFF_TREND  (OFF_SEAS + BB*NN*SEQL)
#define OFF_GIN    (OFF_TREND + BB*NN*SEQL)
#define OFF_GOUT   (OFF_GIN + GG*BB*SEQL)
#define OFF_SEASO  (OFF_GOUT + GG*BB*PREDL)
#define OFF_TRENDO (OFF_SEASO + BB*NN*PREDL)
#define OFF_GX     (OFF_TRENDO + BB*NN*PREDL)
#define OFF_HIST   (OFF_GX + BB*TT*192)
// hist: former [32][336][64] then after [32][96][64]

// output offsets (floats)
#define OUT_FORMER 0
#define OUT_ATTF   (BB*NN*SEQL)
#define OUT_AFTER  (OUT_ATTF + BB*SEQL)
#define OUT_ATTA   (OUT_AFTER + BB*NN*PREDL)

__device__ __forceinline__ float fsig(float x) { return 1.0f/(1.0f + __expf(-x)); }
__device__ __forceinline__ float ftanh(float x) { return 1.0f - 2.0f/(__expf(2.0f*x) + 1.0f); }

// K1: per-group mean over member nodes: g_in[g,b,s]
__global__ __launch_bounds__(384) void k_group_mean(const float* __restrict__ x,
                                                    const int* __restrict__ gi,
                                                    float* __restrict__ g_in) {
    int g = blockIdx.x, b = blockIdx.y;
    __shared__ int sgi[NN];
    __shared__ float scnt;
    int tid = threadIdx.x;
    if (tid < NN) sgi[tid] = gi[tid];
    __syncthreads();
    if (tid == 0) {
        int c = 0;
        for (int n = 0; n < NN; n++) if (sgi[n] == g) c++;
        scnt = (float)c;
    }
    __syncthreads();
    float inv = 1.0f / scnt;
    for (int s = tid; s < SEQL; s += 384) {
        float sum = 0.0f;
        for (int n = 0; n < NN; n++)
            if (sgi[n] == g) sum += x[(b*NN + n)*SEQL + s];
        g_in[(g*BB + b)*SEQL + s] = sum * inv;
    }
}

// K2: g_out[g,b,p] = w_res[g,p,:] . g_in[g,b,:] + b_res[g,p]
__global__ void k_gout(const float* __restrict__ g_in, const float* __restrict__ w_res,
                       const float* __restrict__ b_res, float* __restrict__ g_out) {
    int idx = blockIdx.x*blockDim.x + threadIdx.x;
    if (idx >= GG*BB*PREDL) return;
    int p = idx % PREDL;
    int b = (idx / PREDL) % BB;
    int g = idx / (PREDL*BB);
    const float* gr = g_in + (g*BB + b)*SEQL;
    const float* wr = w_res + (g*PREDL + p)*SEQL;
    float acc = b_res[g*PREDL + p];
    for (int s = 0; s < SEQL; s++) acc += gr[s]*wr[s];
    g_out[idx] = acc;
}

// K3: series decomposition: edge-padded moving average window 25
__global__ void k_decomp(const float* __restrict__ x, float* __restrict__ seasonal,
                         float* __restrict__ trend) {
    int idx = blockIdx.x*blockDim.x + threadIdx.x;
    if (idx >= BB*NN*SEQL) return;
    int t = idx % SEQL;
    int bn = idx / SEQL;
    const float* xr = x + bn*SEQL;
    float s = 0.0f;
    #pragma unroll
    for (int d = -12; d <= 12; d++) {
        int j = t + d;
        j = j < 0 ? 0 : (j >= SEQL ? SEQL-1 : j);
        s += xr[j];
    }
    float tr = s * (1.0f/KWIN);
    trend[idx] = tr;
    seasonal[idx] = xr[t] - tr;
}

// K4: per-node grouped seasonal/trend heads (SEQ->PRED), float4 everywhere
__global__ __launch_bounds__(128) void k_heads(const float* __restrict__ seasonal,
                                               const float* __restrict__ trend,
                                               const int* __restrict__ gi,
                                               const float* __restrict__ w_seas,
                                               const float* __restrict__ b_seas,
                                               const float* __restrict__ w_trend,
                                               const float* __restrict__ b_trend,
                                               float* __restrict__ seas_out,
                                               float* __restrict__ trend_out) {
    int bn = blockIdx.x;
    int n = bn % NN;
    int g = gi[n];
    __shared__ float ss[SEQL];
    __shared__ float st[SEQL];
    for (int s = threadIdx.x; s < SEQL/4; s += 128) {
        ((float4*)ss)[s] = ((const float4*)(seasonal + bn*SEQL))[s];
        ((float4*)st)[s] = ((const float4*)(trend + bn*SEQL))[s];
    }
    __syncthreads();
    int p = threadIdx.x;
    if (p < PREDL) {
        const float4* wsr = (const float4*)(w_seas + (g*PREDL + p)*SEQL);
        const float4* wtr = (const float4*)(w_trend + (g*PREDL + p)*SEQL);
        float a = b_seas[g*PREDL + p];
        float c = b_trend[g*PREDL + p];
        #pragma unroll 4
        for (int s4 = 0; s4 < SEQL/4; s4++) {
            float4 w0 = wsr[s4], w1 = wtr[s4];
            float4 d0 = ((const float4*)ss)[s4], d1 = ((const float4*)st)[s4];
            a += w0.x*d0.x + w0.y*d0.y + w0.z*d0.z + w0.w*d0.w;
            c += w1.x*d1.x + w1.y*d1.y + w1.z*d1.z + w1.w*d1.w;
        }
        seas_out[bn*PREDL + p] = a;
        trend_out[bn*PREDL + p] = c;
    }
}

// K5: node-mean of hidden (34 ch) per (b,t), fused with input-gate GEMM gx.
// All weights read via wave-uniform pointers (-> s_load, no LDS).
__global__ __launch_bounds__(64) void k_hmean_gx(
    const float* __restrict__ seasonal, const float* __restrict__ trend,
    const float* __restrict__ seas_out, const float* __restrict__ trend_out,
    const float* __restrict__ dy, const float* __restrict__ dy_w,
    const float* __restrict__ dy_b, const float* __restrict__ w_ih,
    const float* __restrict__ b_ih, const float* __restrict__ b_hh,
    float* __restrict__ gx)
{
    int bt = blockIdx.x;
    int b = bt / TT, t = bt % TT;
    int lane = threadIdx.x;
    float v[ENDC];
    #pragma unroll
    for (int e = 0; e < ENDC; e++) v[e] = 0.0f;
    #pragma unroll
    for (int q = 0; q < 2; q++) {
        int n = lane + q*64;
        int bn = b*NN + n;
        if (t < SEQL) {
            v[0] += seasonal[bn*SEQL + t];
            v[1] += trend[bn*SEQL + t];
        } else {
            int p = t - SEQL;
            v[0] += seas_out[bn*PREDL + p];
            v[1] += trend_out[bn*PREDL + p];
        }
        const float4* dyr = (const float4*)(dy + ((size_t)bn*TT + t)*DINC);
        float4 d0 = dyr[0], d1 = dyr[1], d2 = dyr[2], d3 = dyr[3];
        float dv[DINC] = {d0.x,d0.y,d0.z,d0.w, d1.x,d1.y,d1.z,d1.w,
                          d2.x,d2.y,d2.z,d2.w, d3.x,d3.y,d3.z,d3.w};
        #pragma unroll 4
        for (int e = 0; e < DEMBC; e++) {
            float a = dy_b[e];                        // uniform -> sgpr
            #pragma unroll
            for (int i = 0; i < DINC; i++) a = fmaf(dv[i], dy_w[e*DINC + i], a);
            v[2+e] += fmaxf(a, 0.0f);
        }
    }
    // butterfly all-reduce: every lane ends with the full sum
    #pragma unroll
    for (int e = 0; e < ENDC; e++) {
        float s = v[e];
        s += __shfl_xor(s, 32, 64);
        s += __shfl_xor(s, 16, 64);
        s += __shfl_xor(s, 8, 64);
        s += __shfl_xor(s, 4, 64);
        s += __shfl_xor(s, 2, 64);
        s += __shfl_xor(s, 1, 64);
        v[e] = s * (1.0f/NN);
    }
    // input-side gates: lane j emits gx[bt][j], [bt][64+j], [bt][128+j]
    // fold b_hh into r,z gates (their hidden-side bias is additive pre-sigmoid)
    #pragma unroll
    for (int gate = 0; gate < 3; gate++) {
        int j = gate*64 + lane;
        const float* w = w_ih + j*ENDC;
        float a = b_ih[j] + (gate < 2 ? b_hh[j] : 0.0f);
        #pragma unroll
        for (int e = 0; e < ENDC; e++) a = fmaf(v[e], w[e], a);
        gx[(size_t)bt*192 + j] = a;
    }
}

// K6: fused MLP (blocks 64..4159) + dual GRU (blocks 0..63, dispatched first so
// the 64 latency-bound GRU waves overlap with the MLP bulk).
// __launch_bounds__(512, 2): min 2 waves/EU -> VGPR cap 256, so the GRU's
// 192-register weight block stays RESIDENT (round-2 spill: VGPR_Count=116).
__global__ __launch_bounds__(512, 2) void k_mlp_gru(
    const float* __restrict__ seasonal, const float* __restrict__ trend,
    const float* __restrict__ seas_out, const float* __restrict__ trend_out,
    const float* __restrict__ g_in, const float* __restrict__ g_out,
    const int* __restrict__ gi, const float* __restrict__ dy,
    const float* __restrict__ dy_w, const float* __restrict__ dy_b,
    const float* __restrict__ w1_end, const float* __restrict__ b1_end,
    const float* __restrict__ w2_end, const float* __restrict__ b2_end,
    const float* __restrict__ gx, const float* __restrict__ w_hh,
    const float* __restrict__ b_hh, const float* __restrict__ w_ap,
    const float* __restrict__ b_ap, float* __restrict__ hist,
    float* __restrict__ out)
{
    __shared__ float hs[2*HIDC];   // GRU h ping-pong (512 B; unused by MLP path)
    int tid = threadIdx.x;

    if (blockIdx.x < 64) {
        // ---------------- GRU path: single wave, weights in registers ----------------
        if (tid >= 64) return;
        int lane = tid;
        int blk = blockIdx.x;
        int b = blk & 31;
        bool former = (blk < 32);
        int steps = former ? SEQL : PREDL;
        int t0 = former ? 0 : SEQL;
        float* hb = hist + (former ? (size_t)b*SEQL*HIDC
                                   : (size_t)BB*SEQL*HIDC + (size_t)b*PREDL*HIDC);
        float wr_[HIDC], wz_[HIDC], wn_[HIDC];
        #pragma unroll
        for (int k = 0; k < HIDC; k++) wr_[k] = w_hh[lane*HIDC + k];
        #pragma unroll
        for (int k = 0; k < HIDC; k++) wz_[k] = w_hh[(lane+64)*HIDC + k];
        #pragma unroll
        for (int k = 0; k < HIDC; k++) wn_[k] = w_hh[(lane+128)*HIDC + k];
        float bhn = b_hh[lane + 128];
        hs[lane] = 0.0f;   // row 0 = h_{-1} = 0 (single wave: lgkmcnt orders)
        float h = 0.0f;
        const float* gxb = gx + (size_t)(b*TT + t0)*192;
        // depth-2 gx prefetch
        float c_r = gxb[lane], c_z = gxb[64+lane], c_n = gxb[128+lane];
        float n_r = 0.f, n_z = 0.f, n_n = 0.f;
        if (steps > 1) { n_r = gxb[192+lane]; n_z = gxb[256+lane]; n_n = gxb[320+lane]; }
        for (int s = 0; s < steps; s++) {
            float p_r = 0.f, p_z = 0.f, p_n = 0.f;
            if (s + 2 < steps) {
                const float* gp = gxb + (size_t)(s+2)*192;
                p_r = gp[lane]; p_z = gp[64+lane]; p_n = gp[128+lane];
            }
            const float* hh = hs + (s & 1)*HIDC;
            float ar = 0.f, az = 0.f, an = 0.f;
            #pragma unroll
            for (int k = 0; k < HIDC; k += 4) {
                float4 h4 = *(const float4*)&hh[k];
                ar = fmaf(h4.x, wr_[k],   ar); az = fmaf(h4.x, wz_[k],   az); an = fmaf(h4.x, wn_[k],   an);
                ar = fmaf(h4.y, wr_[k+1], ar); az = fmaf(h4.y, wz_[k+1], az); an = fmaf(h4.y, wn_[k+1], an);
                ar = fmaf(h4.z, wr_[k+2], ar); az = fmaf(h4.z, wz_[k+2], az); an = fmaf(h4.z, wn_[k+2], an);
                ar = fmaf(h4.w, wr_[k+3], ar); az = fmaf(h4.w, wz_[k+3], az); an = fmaf(h4.w, wn_[k+3], an);
            }
            float r = fsig(c_r + ar);          // b_ih + b_hh folded into gx
            float z = fsig(c_z + az);
            float tg = ftanh(c_n + r*(bhn + an));
            h = (1.0f - z)*tg + z*h;
            hs[((s+1) & 1)*HIDC + lane] = h;
            hb[(size_t)s*HIDC + lane] = h;     // fire-and-forget history store
            c_r = n_r; c_z = n_z; c_n = n_n;
            n_r = p_r; n_z = p_z; n_n = p_n;
        }
        // attention epilogue from history
        float bap = b_ap[0];
        float* attn = out + (former ? (OUT_ATTF + b*SEQL) : (OUT_ATTA + b*PREDL));
        for (int t = lane; t < steps; t += 64) {
            const float* hr = hb + (size_t)t*HIDC;
            float a = 0.f;
            #pragma unroll 16
            for (int k = 0; k < HIDC; k++) a = fmaf(hr[k], w_ap[k], a);
            attn[t] = fsig(a + bap);
        }
        return;
    }

    // ---------------- MLP path: no LDS, no barriers; weights via s_load ----------------
    int bn = blockIdx.x - 64;
    int b = bn / NN, n = bn % NN;
    int g = gi[n];                              // uniform -> scalar
    int t = tid;
    if (t >= TT) return;

    const float4* dyr = (const float4*)(dy + ((size_t)bn*TT + t)*DINC);
    float4 d0 = dyr[0], d1 = dyr[1], d2 = dyr[2], d3 = dyr[3];
    float dv[DINC] = {d0.x,d0.y,d0.z,d0.w, d1.x,d1.y,d1.z,d1.w,
                      d2.x,d2.y,d2.z,d2.w, d3.x,d3.y,d3.z,d3.w};
    float hv[36];
    #pragma unroll 4
    for (int e = 0; e < DEMBC; e++) {
        float a = dy_b[e];                      // uniform -> sgpr
        #pragma unroll
        for (int i = 0; i < DINC; i++) a = fmaf(dv[i], dy_w[e*DINC + i], a);
        hv[2+e] = fmaxf(a, 0.0f);
    }
    float addv;
    if (t < SEQL) {
        hv[0] = seasonal[bn*SEQL + t];
        hv[1] = trend[bn*SEQL + t];
        addv = g_in[(g*BB + b)*SEQL + t];
    } else {
        int p = t - SEQL;
        hv[0] = seas_out[bn*PREDL + p];
        hv[1] = trend_out[bn*PREDL + p];
        addv = g_out[(g*BB + b)*PREDL + p];
    }
    float acc = b2_end[g];
    const float* w1g = w1_end + g*HIDC*ENDC;
    const float* b1g = b1_end + g*HIDC;
    const float* w2g = w2_end + g*HIDC;
    #pragma unroll 4
    for (int hq = 0; hq < HIDC; hq++) {
        const float* wrow = w1g + hq*ENDC;      // uniform row -> s_load
        float a = b1g[hq];
        #pragma unroll
        for (int e = 0; e < ENDC; e++) a = fmaf(hv[e], wrow[e], a);
        acc = fmaf(fmaxf(a, 0.0f), w2g[hq], acc);
    }
    acc += addv;
    if (t < SEQL) out[OUT_FORMER + bn*SEQL + t] = acc;
    else          out[OUT_AFTER + bn*PREDL + (t - SEQL)] = acc;
}

extern "C" void kernel_launch(void* const* d_in, const int* in_sizes, int n_in,
                              void* d_out, int out_size, void* d_ws, size_t ws_size,
                              hipStream_t stream) {
    (void)in_sizes; (void)n_in; (void)out_size; (void)ws_size;
    const float* x       = (const float*)d_in[0];
    const float* dy      = (const float*)d_in[1];
    const int*   gi      = (const int*)  d_in[2];
    const float* dy_w    = (const float*)d_in[3];
    const float* dy_b    = (const float*)d_in[4];
    const float* w_seas  = (const float*)d_in[5];
    const float* b_seas  = (const float*)d_in[6];
    const float* w_trend = (const float*)d_in[7];
    const float* b_trend = (const float*)d_in[8];
    const float* w_res   = (const float*)d_in[9];
    const float* b_res   = (const float*)d_in[10];
    const float* w1_end  = (const float*)d_in[11];
    const float* b1_end  = (const float*)d_in[12];
    const float* w2_end  = (const float*)d_in[13];
    const float* b2_end  = (const float*)d_in[14];
    const float* w_ih    = (const float*)d_in[15];
    const float* w_hh    = (const float*)d_in[16];
    const float* b_ih    = (const float*)d_in[17];
    const float* b_hh    = (const float*)d_in[18];
    const float* w_ap    = (const float*)d_in[19];
    const float* b_ap    = (const float*)d_in[20];
    float* ws  = (float*)d_ws;
    float* out = (float*)d_out;

    hipLaunchKernelGGL(k_group_mean, dim3(GG, BB), dim3(384), 0, stream, x, gi, ws + OFF_GIN);
    hipLaunchKernelGGL(k_decomp, dim3((BB*NN*SEQL + 255)/256), dim3(256), 0, stream,
                       x, ws + OFF_SEAS, ws + OFF_TREND);
    hipLaunchKernelGGL(k_gout, dim3((GG*BB*PREDL + 255)/256), dim3(256), 0, stream,
                       ws + OFF_GIN, w_res, b_res, ws + OFF_GOUT);
    hipLaunchKernelGGL(k_heads, dim3(BB*NN), dim3(128), 0, stream,
                       ws + OFF_SEAS, ws + OFF_TREND, gi, w_seas, b_seas, w_trend, b_trend,
                       ws + OFF_SEASO, ws + OFF_TRENDO);
    hipLaunchKernelGGL(k_hmean_gx, dim3(BB*TT), dim3(64), 0, stream,
                       ws + OFF_SEAS, ws + OFF_TREND, ws + OFF_SEASO, ws + OFF_TRENDO,
                       dy, dy_w, dy_b, w_ih, b_ih, b_hh, ws + OFF_GX);
    hipLaunchKernelGGL(k_mlp_gru, dim3(64 + BB*NN), dim3(512), 0, stream,
                       ws + OFF_SEAS, ws + OFF_TREND, ws + OFF_SEASO, ws + OFF_TRENDO,
                       ws + OFF_GIN, ws + OFF_GOUT, gi, dy, dy_w, dy_b,
                       w1_end, b1_end, w2_end, b2_end,
                       ws + OFF_GX, w_hh, b_hh, w_ap, b_ap, ws + OFF_HIST, out);
}